// Round 5
// baseline (77.190 us; speedup 1.0000x reference)
//
#include <hip/hip_runtime.h>
#include <hip/hip_bf16.h>

#define VOCAB 50257
#define NTAGS 50
#define EMB   128
#define NTOK  262144
#define KD    640     // (2*CTX+1) * EMB
#define WPAD  64      // tags padded to 4 MFMA m-tiles

#define TPB   64      // 1 wave per block
#define TOKPB 60      // tokens per block (64 staged rows = exactly 16 KB LDS)
#define ROWS  64      // 60 + 4 halo staged rows -> 16384 B
#define STEPS 20      // 5 positions x 4 k-chunks

typedef __attribute__((ext_vector_type(4))) float f32x4;
typedef __attribute__((ext_vector_type(8))) short bf16x8;

__device__ __forceinline__ ushort f2bf(float f) {
    union { float f; unsigned u; } v; v.f = f;
    unsigned u = v.u;
    return (ushort)((u + 0x7fffu + ((u >> 16) & 1u)) >> 16);  // RNE
}

__device__ __forceinline__ void gload_lds16(const void* g, void* l) {
    __builtin_amdgcn_global_load_lds(
        (const __attribute__((address_space(1))) unsigned*)g,
        (__attribute__((address_space(3))) unsigned*)l, 16, 0, 0);
}

// fused conversions: emb fp32 -> bf16 (+ zero row at VOCAB),
// W fp32 [50][640] -> bf16 [64][640] (pad rows 0), bias -> padded [64] fp32
__global__ void conv_k(const float* __restrict__ emb, const float* __restrict__ W,
                       const float* __restrict__ b,
                       ushort* __restrict__ embb, ushort* __restrict__ wb,
                       float* __restrict__ biasp) {
    const int etotal = (VOCAB + 1) * EMB;
    int idx = (blockIdx.x * blockDim.x + threadIdx.x) * 4;
    if (idx < etotal) {
        float4 v = {0.f, 0.f, 0.f, 0.f};
        if (idx < VOCAB * EMB) v = *(const float4*)(emb + idx);
        ushort4 o = { f2bf(v.x), f2bf(v.y), f2bf(v.z), f2bf(v.w) };
        *(ushort4*)(embb + idx) = o;
    } else if (idx < etotal + WPAD * KD) {
        int wi = idx - etotal;
        #pragma unroll
        for (int k = 0; k < 4; ++k) {
            int j = wi + k;
            int tag = j / KD;
            wb[j] = f2bf(tag < NTAGS ? W[j] : 0.f);
        }
    } else {
        int wi = idx - etotal - WPAD * KD;
        if (wi < WPAD) {
            #pragma unroll
            for (int k = 0; k < 4; ++k) {
                int j = wi + k;
                biasp[j] = (j < NTAGS) ? b[j] : 0.f;
            }
        }
    }
}

__global__ __launch_bounds__(TPB, 2)
void tagger_k(const int* __restrict__ tokens, const ushort* __restrict__ embb,
              const ushort* __restrict__ Wb, const float* __restrict__ biasp,
              float* __restrict__ out) {
    __shared__ ushort smem[ROWS * EMB];   // 64 rows x 256 B = 16384 B exactly

    const int lane = threadIdx.x & 63;
    const int c = lane & 15;   // operand non-k selector / D col (token-in-tile)
    const int q = lane >> 4;   // k-chunk selector / D row-group (tag-sub)
    const int bb = blockIdx.x * TOKPB;
    const int rsub = q;

    // token-tile offsets: last tile overlaps (60 tokens, 16-row MFMA tiles)
    const int O[4] = {0, 16, 32, 44};

    // ---- token ids for the 16 staging groups (batched, independent) ----
    int tokid[16];
    #pragma unroll
    for (int g = 0; g < 16; ++g) {
        int t = bb - 2 + g * 4 + rsub;
        tokid[g] = (t >= 0 && t < NTOK) ? tokens[t] : VOCAB;   // VOCAB = zero row
    }

    // ---- W fragment bases (W is the A operand now; same loads as before) ----
    const ushort* bp[4];
    #pragma unroll
    for (int mt = 0; mt < 4; ++mt)
        bp[mt] = Wb + (mt * 16 + c) * KD + q * 8;

    // ---- prefetch W for steps 0..3 (independent of staging) ----
    bf16x8 Wr[4][4];
    #pragma unroll
    for (int s = 0; s < 4; ++s)
        #pragma unroll
        for (int mt = 0; mt < 4; ++mt)
            Wr[s][mt] = *(const bf16x8*)(bp[mt] + (s >> 2) * 128 + (s & 3) * 32);

    // ---- bias: 4 tags per (mt,q) as float4 from padded bias ----
    float bvv[4][4];
    #pragma unroll
    for (int mt = 0; mt < 4; ++mt) {
        float4 t4 = *(const float4*)(biasp + mt * 16 + q * 4);
        bvv[mt][0] = t4.x; bvv[mt][1] = t4.y; bvv[mt][2] = t4.z; bvv[mt][3] = t4.w;
    }

    // ---- stage rows [bb-2, bb+62) into LDS, chunk-swizzled via global source ----
    {
        const int pc = c;
        #pragma unroll
        for (int g = 0; g < 16; ++g) {
            int i = g * 4 + rsub;
            int sc = pc ^ (i & 7);
            gload_lds16(embb + (size_t)tokid[g] * EMB + sc * 8, (char*)smem + g * 1024);
        }
    }
    __syncthreads();   // 1-wave block: effectively the vmcnt drain

    f32x4 acc[4][4];   // [mt=tag tile][nt=token tile]
    #pragma unroll
    for (int mt = 0; mt < 4; ++mt)
        #pragma unroll
        for (int nt = 0; nt < 4; ++nt)
            acc[mt][nt] = (f32x4){0.f, 0.f, 0.f, 0.f};

    // ---- E (emb, B operand) prefetch steps 0,1 ----
    bf16x8 Er[2][4];
    #pragma unroll
    for (int s = 0; s < 2; ++s) {
        int p = s >> 2, kk = s & 3;
        #pragma unroll
        for (int nt = 0; nt < 4; ++nt) {
            int r  = O[nt] + c + p;
            int ch = (4 * kk + q) ^ (r & 7);
            Er[s][nt] = *(const bf16x8*)((const char*)smem + r * 256 + ch * 16);
        }
    }

    // ---- pipelined k-loop: MFMA(s) | issue W(s+4) | issue E(s+2) ----
    #pragma unroll
    for (int s = 0; s < STEPS; ++s) {
        __builtin_amdgcn_s_setprio(1);
        #pragma unroll
        for (int mt = 0; mt < 4; ++mt)
            #pragma unroll
            for (int nt = 0; nt < 4; ++nt)
                acc[mt][nt] = __builtin_amdgcn_mfma_f32_16x16x32_bf16(
                    Wr[s & 3][mt], Er[s & 1][nt], acc[mt][nt], 0, 0, 0);
        __builtin_amdgcn_s_setprio(0);
        if (s + 4 < STEPS) {
            const int t = s + 4, p = t >> 2, kk = t & 3;
            #pragma unroll
            for (int mt = 0; mt < 4; ++mt)
                Wr[s & 3][mt] = *(const bf16x8*)(bp[mt] + p * 128 + kk * 32);
        }
        if (s + 2 < STEPS) {
            const int t = s + 2, p = t >> 2, kk = t & 3;
            #pragma unroll
            for (int nt = 0; nt < 4; ++nt) {
                int r  = O[nt] + c + p;
                int ch = (4 * kk + q) ^ (r & 7);
                Er[s & 1][nt] = *(const bf16x8*)((const char*)smem + r * 256 + ch * 16);
            }
        }
    }

    // ---- epilogue: D[tag][token]; lane holds 16 tags x 4 tokens.
    //      per-token softmax reduce = local 16 regs + shfl_xor 16,32 ----
    #pragma unroll
    for (int nt = 0; nt < 4; ++nt) {
        const int token = bb + O[nt] + c;
        float x[4][4];
        float m = -1e30f;
        #pragma unroll
        for (int mt = 0; mt < 4; ++mt)
            #pragma unroll
            for (int j = 0; j < 4; ++j) {
                float v = acc[mt][nt][j] + bvv[mt][j];
                if (mt == 3 && !(q == 0 && j < 2)) v = -1e30f;  // tags >= 50 masked
                x[mt][j] = v;
                m = fmaxf(m, v);
            }
        m = fmaxf(m, __shfl_xor(m, 16));
        m = fmaxf(m, __shfl_xor(m, 32));
        float ssum = 0.f;
        #pragma unroll
        for (int mt = 0; mt < 4; ++mt)
            #pragma unroll
            for (int j = 0; j < 4; ++j)
                ssum += __expf(x[mt][j] - m);   // masked -> exp(-huge) = 0
        ssum += __shfl_xor(ssum, 16);
        ssum += __shfl_xor(ssum, 32);
        const float L = m + __logf(ssum);
        if (token < NTOK) {
            float* op = out + (size_t)token * NTAGS;
            #pragma unroll
            for (int mt = 0; mt < 3; ++mt) {
                float4 st = { x[mt][0] - L, x[mt][1] - L, x[mt][2] - L, x[mt][3] - L };
                *(float4*)(op + mt * 16 + q * 4) = st;
            }
            if (q == 0) {
                float2 st2 = { x[3][0] - L, x[3][1] - L };   // tags 48,49
                *(float2*)(op + 48) = st2;
            }
        }
    }
}

extern "C" void kernel_launch(void* const* d_in, const int* in_sizes, int n_in,
                              void* d_out, int out_size, void* d_ws, size_t ws_size,
                              hipStream_t stream) {
    const int*   tokens = (const int*)d_in[0];
    const float* emb    = (const float*)d_in[1];
    const float* W      = (const float*)d_in[2];
    const float* b      = (const float*)d_in[3];
    float* out = (float*)d_out;

    ushort* embb  = (ushort*)d_ws;                              // (VOCAB+1)*128 bf16
    ushort* Wb    = embb + (size_t)(VOCAB + 1) * EMB;           // 64*640 bf16
    float*  biasp = (float*)(Wb + (size_t)WPAD * KD);           // 64 fp32 padded bias

    {
        const int etotal = (VOCAB + 1) * EMB;
        const int total4 = (etotal + WPAD * KD + WPAD) / 4;
        conv_k<<<(total4 + 255) / 256, 256, 0, stream>>>(emb, W, b, embb, Wb, biasp);
    }
    {
        const int nblk = (NTOK + TOKPB - 1) / TOKPB;            // 4370
        tagger_k<<<nblk, TPB, 0, stream>>>(tokens, embb, Wb, biasp, out);
    }
}